// Round 7
// baseline (546.332 us; speedup 1.0000x reference)
//
#include <hip/hip_runtime.h>
#include <hip/hip_bf16.h>
#include <hip/hip_fp16.h>
#include <float.h>

#define D 128
#define NGRAPHS 64
#define BKSHIFT 9
#define BKNODES 512     // nodes per bucket
#define MAXBK 256       // max buckets (N<=131072)
#define PCH 4096        // edges per partition block (256 thr x 16)

// ---- ordered-float encoding for atomicMax on unsigned ----
__device__ __forceinline__ unsigned fkey(float f){
  unsigned u = __float_as_uint(f);
  return (u & 0x80000000u) ? ~u : (u | 0x80000000u);
}
__device__ __forceinline__ float funkey(unsigned k){
  unsigned u = (k & 0x80000000u) ? (k ^ 0x80000000u) : ~k;
  return __uint_as_float(u);
}

// A) bucket histogram: bcnt[b] = #edges with dst in bucket b
__global__ __launch_bounds__(256) void k_bhist(const int* __restrict__ dst,
    int* __restrict__ bcnt, int E){
  __shared__ int h[MAXBK];
  int t = threadIdx.x;
  for (int i = t; i < MAXBK; i += 256) h[i] = 0;
  __syncthreads();
  int e0 = blockIdx.x * PCH;
  #pragma unroll
  for (int j = 0; j < PCH / 256; j++){
    int e = e0 + t + j * 256;
    if (e < E) atomicAdd(&h[dst[e] >> BKSHIFT], 1);
  }
  __syncthreads();
  for (int i = t; i < MAXBK; i += 256) if (h[i]) atomicAdd(&bcnt[i], h[i]);
}

// B) scan bucket counts -> bOff[nbk+1], bCur; also row_ptr[N]=E
__global__ __launch_bounds__(256) void k_bscan(const int* __restrict__ bcnt,
    int* __restrict__ bOff, int* __restrict__ bCur, int* __restrict__ row_ptr,
    int nbk, int N, int E){
  __shared__ int sh[256];
  int t = threadIdx.x;
  int v = (t < nbk) ? bcnt[t] : 0;
  sh[t] = v; __syncthreads();
  for (int off = 1; off < 256; off <<= 1){
    int x = (t >= off) ? sh[t - off] : 0;
    __syncthreads();
    sh[t] += x;
    __syncthreads();
  }
  if (t < nbk){ int ex = sh[t] - v; bOff[t] = ex; bCur[t] = ex; }
  if (t == 0){ bOff[nbk] = E; row_ptr[N] = E; }
}

// C) partition edges into bucket-grouped epart[] with LDS-staged coalesced writes
__global__ __launch_bounds__(256) void k_part(const int* __restrict__ src,
    const int* __restrict__ dst, int* __restrict__ bCur,
    uint2* __restrict__ epart, int E){
  __shared__ int scnt[MAXBK], soff[MAXBK], sbase[MAXBK], scur[MAXBK];
  __shared__ int stmp[256];
  __shared__ uint2 stage[PCH];   // 32 KB
  int t = threadIdx.x;
  int e0 = blockIdx.x * PCH;
  int eN = E - e0; if (eN > PCH) eN = PCH;
  for (int i = t; i < MAXBK; i += 256){ scnt[i] = 0; scur[i] = 0; }
  __syncthreads();
  uint2 mye[PCH / 256];
  #pragma unroll
  for (int j = 0; j < PCH / 256; j++){
    int e = e0 + t + j * 256;
    if (e < E){
      mye[j].x = (unsigned)src[e];
      mye[j].y = (unsigned)dst[e];
      atomicAdd(&scnt[mye[j].y >> BKSHIFT], 1);
    }
  }
  __syncthreads();
  // exclusive scan of scnt (256 == MAXBK lanes)
  int v = scnt[t];
  stmp[t] = v; __syncthreads();
  for (int off = 1; off < 256; off <<= 1){
    int x = (t >= off) ? stmp[t - off] : 0;
    __syncthreads();
    stmp[t] += x;
    __syncthreads();
  }
  soff[t] = stmp[t] - v;
  // reserve this block's run in each bucket
  if (v > 0) sbase[t] = atomicAdd(&bCur[t], v);
  __syncthreads();
  // place edges into stage, grouped by bucket
  #pragma unroll
  for (int j = 0; j < PCH / 256; j++){
    int e = e0 + t + j * 256;
    if (e < E){
      int b = mye[j].y >> BKSHIFT;
      int l = atomicAdd(&scur[b], 1);
      stage[soff[b] + l] = mye[j];
    }
  }
  __syncthreads();
  // write out: consecutive threads -> consecutive slots within per-bucket runs
  for (int j = t; j < eN; j += 256){
    uint2 ed = stage[j];
    int b = (int)(ed.y >> BKSHIFT);
    epart[(size_t)sbase[b] + (j - soff[b])] = ed;
  }
}

// D) per-bucket CSR build: row_ptr, col, dinv — all state in LDS, confined writes
__global__ __launch_bounds__(256) void k_bfill(const uint2* __restrict__ epart,
    const int* __restrict__ bOff, int* __restrict__ row_ptr,
    int* __restrict__ col, float* __restrict__ dinv, int N){
  __shared__ int hc[BKNODES], off[BKNODES], cur[BKNODES];
  __shared__ int stmp[256];
  int b = blockIdx.x, t = threadIdx.x;
  int base = bOff[b], cntE = bOff[b + 1] - base;
  int node0 = b << BKSHIFT;
  int nloc = N - node0; if (nloc > BKNODES) nloc = BKNODES;
  for (int i = t; i < BKNODES; i += 256) hc[i] = 0;
  __syncthreads();
  for (int j = t; j < cntE; j += 256){
    uint2 ed = epart[(size_t)base + j];
    atomicAdd(&hc[ed.y - node0], 1);
  }
  __syncthreads();
  // exclusive scan of 512 via pairs on 256 threads
  int a0 = hc[2 * t], a1 = hc[2 * t + 1];
  int s = a0 + a1;
  stmp[t] = s; __syncthreads();
  for (int o = 1; o < 256; o <<= 1){
    int x = (t >= o) ? stmp[t - o] : 0;
    __syncthreads();
    stmp[t] += x;
    __syncthreads();
  }
  int ex = stmp[t] - s;
  off[2 * t] = ex; off[2 * t + 1] = ex + a0;
  __syncthreads();
  for (int i = t; i < nloc; i += 256){
    row_ptr[node0 + i] = base + off[i];
    dinv[node0 + i]    = rsqrtf((float)hc[i] + 1.0f);
    cur[i] = off[i];
  }
  __syncthreads();
  for (int j = t; j < cntE; j += 256){
    uint2 ed = epart[(size_t)base + j];
    int p = atomicAdd(&cur[ed.y - node0], 1);
    col[base + p] = (int)ed.x;
  }
}

// E) fp32 -> fp16 convert (x -> xh), 8 elems/thread
__global__ __launch_bounds__(256) void k_cvt(const float* __restrict__ in,
    __half* __restrict__ outp, int n8){
  int i = blockIdx.x * 256 + threadIdx.x;
  if (i >= n8) return;
  float4 a = *(const float4*)&in[(size_t)i * 8];
  float4 b = *(const float4*)&in[(size_t)i * 8 + 4];
  __half2 p0 = __floats2half2_rn(a.x, a.y);
  __half2 p1 = __floats2half2_rn(a.z, a.w);
  __half2 p2 = __floats2half2_rn(b.x, b.y);
  __half2 p3 = __floats2half2_rn(b.z, b.w);
  uint4 u;
  u.x = *(unsigned*)&p0; u.y = *(unsigned*)&p1;
  u.z = *(unsigned*)&p2; u.w = *(unsigned*)&p3;
  *(uint4*)&outp[(size_t)i * 8] = u;
}

// 5) GEMM: C[M,128] = A[M,128] @ W[128,128]; A fp16, W fp32, fp32 math, out fp16.
__global__ __launch_bounds__(256) void gemm128(const __half* __restrict__ A,
    const float* __restrict__ W, __half* __restrict__ C, int M){
  __shared__ float Ws[32 * 128];
  __shared__ float At[32 * 64];
  int t = threadIdx.x;
  int rowBase = blockIdx.x * 64;
  int c0 = (t & 31) * 4;
  int r0 = (t >> 5) * 8;
  float acc[8][4] = {};
  for (int k0 = 0; k0 < 128; k0 += 32){
    const float* wt = W + k0 * 128;
    #pragma unroll
    for (int j = 0; j < 4; j++){
      int idx = j * 1024 + t * 4;
      *(float4*)&Ws[idx] = *(const float4*)&wt[idx];
    }
    #pragma unroll
    for (int j = 0; j < 2; j++){
      int lid = t + j * 256;
      int row = lid >> 3;
      int kk  = (lid & 7) * 4;
      int gr = rowBase + row; if (gr >= M) gr = M - 1;
      uint2 u = *(const uint2*)&A[(size_t)gr * D + k0 + kk];
      __half2 h0 = *(__half2*)&u.x;
      __half2 h1 = *(__half2*)&u.y;
      float2 f0 = __half22float2(h0);
      float2 f1 = __half22float2(h1);
      At[(kk + 0) * 64 + row] = f0.x;
      At[(kk + 1) * 64 + row] = f0.y;
      At[(kk + 2) * 64 + row] = f1.x;
      At[(kk + 3) * 64 + row] = f1.y;
    }
    __syncthreads();
    #pragma unroll
    for (int kk = 0; kk < 32; kk++){
      float4 b = *(float4*)&Ws[kk * 128 + c0];
      float4 a0 = *(float4*)&At[kk * 64 + r0];
      float4 a1 = *(float4*)&At[kk * 64 + r0 + 4];
      float av[8] = {a0.x, a0.y, a0.z, a0.w, a1.x, a1.y, a1.z, a1.w};
      #pragma unroll
      for (int r = 0; r < 8; r++){
        acc[r][0] += av[r] * b.x;
        acc[r][1] += av[r] * b.y;
        acc[r][2] += av[r] * b.z;
        acc[r][3] += av[r] * b.w;
      }
    }
    __syncthreads();
  }
  #pragma unroll
  for (int r = 0; r < 8; r++){
    int gr = rowBase + r0 + r;
    if (gr < M){
      __half2 p0 = __floats2half2_rn(acc[r][0], acc[r][1]);
      __half2 p1 = __floats2half2_rn(acc[r][2], acc[r][3]);
      uint2 u;
      u.x = *(unsigned*)&p0;
      u.y = *(unsigned*)&p1;
      *(uint2*)&C[(size_t)gr * D + c0] = u;
    }
  }
}

// accumulate 8 halves * w into acc[8]; (float)h * w + acc -> v_fma_mix_f32
__device__ __forceinline__ void accm(float* acc, uint4 u, float w){
  union { uint4 u; _Float16 h[8]; } cv;
  cv.u = u;
  #pragma unroll
  for (int k = 0; k < 8; k++)
    acc[k] += (float)cv.h[k] * w;
}

// 6) CSR aggregation v4: one wave per node, 4 gather chains/lane, fma_mix accumulate.
//    lane = way(0..3) x cg16(0..15); lane loads uint4 = 8 halves; 16 lanes = row.
//    relu=1 -> write fp16 to outh; relu=0 -> write fp32 to outf.
__global__ __launch_bounds__(256) void k_agg(const __half* __restrict__ t,
    const int* __restrict__ row_ptr, const int* __restrict__ col,
    const float* __restrict__ dinv, const float* __restrict__ bias,
    float* __restrict__ outf, __half* __restrict__ outh, int relu, int N){
  int node = blockIdx.x * 4 + (threadIdx.x >> 6);
  if (node >= N) return;
  int lane = threadIdx.x & 63;
  int way  = lane >> 4;          // 0..3
  int cg   = (lane & 15) * 8;    // first col of this lane's 8-half group
  float di = dinv[node];
  int beg = row_ptr[node], end = row_ptr[node + 1];
  float acc[8] = {0.f,0.f,0.f,0.f,0.f,0.f,0.f,0.f};
  int j = beg + way;
  // main loop: 4 independent gather chains in flight
  for (; j + 12 < end; j += 16){
    int s0 = col[j], s1 = col[j + 4], s2 = col[j + 8], s3 = col[j + 12];
    float w0 = dinv[s0] * di;
    float w1 = dinv[s1] * di;
    float w2 = dinv[s2] * di;
    float w3 = dinv[s3] * di;
    uint4 u0 = *(const uint4*)&t[(size_t)s0 * D + cg];
    uint4 u1 = *(const uint4*)&t[(size_t)s1 * D + cg];
    uint4 u2 = *(const uint4*)&t[(size_t)s2 * D + cg];
    uint4 u3 = *(const uint4*)&t[(size_t)s3 * D + cg];
    accm(acc, u0, w0);
    accm(acc, u1, w1);
    accm(acc, u2, w2);
    accm(acc, u3, w3);
  }
  for (; j < end; j += 4){
    int s = col[j];
    float w = dinv[s] * di;
    uint4 u = *(const uint4*)&t[(size_t)s * D + cg];
    accm(acc, u, w);
  }
  // reduce across the 4 ways (lanes 16, 32 apart)
  #pragma unroll
  for (int k = 0; k < 8; k++){
    acc[k] += __shfl_xor(acc[k], 16, 64);
    acc[k] += __shfl_xor(acc[k], 32, 64);
  }
  if (way == 0){
    uint4 su = *(const uint4*)&t[(size_t)node * D + cg];
    union { uint4 u; _Float16 h[8]; } sv; sv.u = su;
    float dii = di * di;
    float4 b0 = *(const float4*)&bias[cg];
    float4 b1 = *(const float4*)&bias[cg + 4];
    float bb[8] = {b0.x, b0.y, b0.z, b0.w, b1.x, b1.y, b1.z, b1.w};
    float o[8];
    #pragma unroll
    for (int k = 0; k < 8; k++)
      o[k] = acc[k] + (float)sv.h[k] * dii + bb[k];
    if (relu){
      #pragma unroll
      for (int k = 0; k < 8; k++) o[k] = fmaxf(o[k], 0.f);
      __half2 p0 = __floats2half2_rn(o[0], o[1]);
      __half2 p1 = __floats2half2_rn(o[2], o[3]);
      __half2 p2 = __floats2half2_rn(o[4], o[5]);
      __half2 p3 = __floats2half2_rn(o[6], o[7]);
      uint4 u;
      u.x = *(unsigned*)&p0; u.y = *(unsigned*)&p1;
      u.z = *(unsigned*)&p2; u.w = *(unsigned*)&p3;
      *(uint4*)&outh[(size_t)node * D + cg] = u;
    } else {
      *(float4*)&outf[(size_t)node * D + cg]     = *(float4*)&o[0];
      *(float4*)&outf[(size_t)node * D + cg + 4] = *(float4*)&o[4];
    }
  }
}

// 7) chunked segment-max into ordered-uint atomicMax (batch is sorted)
__global__ __launch_bounds__(128) void k_pool(const float* __restrict__ h,
    const int* __restrict__ batch, unsigned* __restrict__ pk, int N){
  int d = threadIdx.x;
  int n0 = blockIdx.x * 128;
  int nEnd = n0 + 128; if (nEnd > N) nEnd = N;
  float cur = -FLT_MAX;
  int curg = batch[n0];
  for (int n = n0; n < nEnd; n++){
    int g = batch[n];
    if (g != curg){
      atomicMax(&pk[curg * D + d], fkey(cur));
      cur = -FLT_MAX; curg = g;
    }
    cur = fmaxf(cur, h[(size_t)n * D + d]);
  }
  atomicMax(&pk[curg * D + d], fkey(cur));
}

// 8) final: out[64,2] = pooled @ Wf + bf
__global__ __launch_bounds__(128) void k_final(const unsigned* __restrict__ pk,
    const float* __restrict__ Wf, const float* __restrict__ bf,
    float* __restrict__ out){
  int t = threadIdx.x;
  int g = t >> 1, c = t & 1;
  float s = bf[c];
  for (int k = 0; k < D; k++)
    s += funkey(pk[g * D + k]) * Wf[k * 2 + c];
  out[g * 2 + c] = s;
}

extern "C" void kernel_launch(void* const* d_in, const int* in_sizes, int n_in,
                              void* d_out, int out_size, void* d_ws, size_t ws_size,
                              hipStream_t stream){
  const float* x   = (const float*)d_in[0];
  const int*   ei  = (const int*)d_in[1];
  const int*   bat = (const int*)d_in[2];
  const float* W0  = (const float*)d_in[3];
  const float* b0  = (const float*)d_in[4];
  const float* W1  = (const float*)d_in[5];
  const float* b1  = (const float*)d_in[6];
  const float* W2  = (const float*)d_in[7];
  const float* b2  = (const float*)d_in[8];
  const float* Wf  = (const float*)d_in[9];
  const float* bf  = (const float*)d_in[10];
  int N = in_sizes[0] / D;
  int E = in_sizes[1] / 2;
  const int* srcp = ei;
  const int* dstp = ei + E;
  int nbk   = (N + BKNODES - 1) / BKNODES;
  int npart = (E + PCH - 1) / PCH;

  char* p = (char*)d_ws;
  auto alloc = [&](size_t bytes)->char*{
    char* r = p; p += (bytes + 255) & ~(size_t)255; return r;
  };
  float*    dinv    = (float*)alloc((size_t)N * 4);
  int*      row_ptr = (int*)alloc((size_t)(N + 1) * 4);
  int*      col     = (int*)alloc((size_t)E * 4);
  uint2*    epart   = (uint2*)alloc((size_t)E * 8);
  __half*   tmp     = (__half*)alloc((size_t)N * D * 2);   // gemm out
  __half*   h16     = (__half*)alloc((size_t)N * D * 2);   // xh / agg out L0,L1
  float*    hbuf    = (float*)alloc((size_t)N * D * 4);    // agg out L2 (fp32)
  unsigned* pk      = (unsigned*)alloc((size_t)NGRAPHS * D * 4);
  int*      bcnt    = (int*)alloc((size_t)MAXBK * 4);
  int*      bOff    = (int*)alloc((size_t)(MAXBK + 1) * 4);
  int*      bCur    = (int*)alloc((size_t)MAXBK * 4);

  hipMemsetAsync(bcnt, 0, (size_t)MAXBK * 4, stream);
  hipMemsetAsync(pk, 0, (size_t)NGRAPHS * D * 4, stream);

  // x -> fp16 (h16 doubles as xh; consumed by L0 gemm before L0 agg rewrites it)
  int n8 = N * D / 8;
  k_cvt<<<(n8 + 255) / 256, 256, 0, stream>>>(x, h16, n8);

  k_bhist<<<npart, 256, 0, stream>>>(dstp, bcnt, E);
  k_bscan<<<1, 256, 0, stream>>>(bcnt, bOff, bCur, row_ptr, nbk, N, E);
  k_part<<<npart, 256, 0, stream>>>(srcp, dstp, bCur, epart, E);
  k_bfill<<<nbk, 256, 0, stream>>>(epart, bOff, row_ptr, col, dinv, N);

  int gblocks = (N + 63) / 64;
  int ablocks = (N + 3) / 4;
  // layer 0
  gemm128<<<gblocks, 256, 0, stream>>>(h16, W0, tmp, N);
  k_agg<<<ablocks, 256, 0, stream>>>(tmp, row_ptr, col, dinv, b0, nullptr, h16, 1, N);
  // layer 1
  gemm128<<<gblocks, 256, 0, stream>>>(h16, W1, tmp, N);
  k_agg<<<ablocks, 256, 0, stream>>>(tmp, row_ptr, col, dinv, b1, nullptr, h16, 1, N);
  // layer 2 (no relu, fp32 out for pool)
  gemm128<<<gblocks, 256, 0, stream>>>(h16, W2, tmp, N);
  k_agg<<<ablocks, 256, 0, stream>>>(tmp, row_ptr, col, dinv, b2, hbuf, nullptr, 0, N);
  // pool + classifier
  k_pool<<<(N + 127) / 128, 128, 0, stream>>>(hbuf, bat, pk, N);
  k_final<<<1, 128, 0, stream>>>(pk, Wf, bf, (float*)d_out);
}

// Round 8
// 450.279 us; speedup vs baseline: 1.2133x; 1.2133x over previous
//
#include <hip/hip_runtime.h>
#include <hip/hip_bf16.h>
#include <hip/hip_fp16.h>
#include <float.h>

#define D 128
#define NGRAPHS 64
#define BKSHIFT 9
#define BKNODES 512     // nodes per bucket
#define MAXBK 256       // max buckets (N<=131072)
#define PCH 4096        // edges per partition block (256 thr x 16)

typedef _Float16 h8 __attribute__((ext_vector_type(8)));
typedef float f4 __attribute__((ext_vector_type(4)));

// ---- ordered-float encoding for atomicMax on unsigned ----
__device__ __forceinline__ unsigned fkey(float f){
  unsigned u = __float_as_uint(f);
  return (u & 0x80000000u) ? ~u : (u | 0x80000000u);
}
__device__ __forceinline__ float funkey(unsigned k){
  unsigned u = (k & 0x80000000u) ? (k ^ 0x80000000u) : ~k;
  return __uint_as_float(u);
}

// A) bucket histogram: bcnt[b] = #edges with dst in bucket b
__global__ __launch_bounds__(256) void k_bhist(const int* __restrict__ dst,
    int* __restrict__ bcnt, int E){
  __shared__ int h[MAXBK];
  int t = threadIdx.x;
  for (int i = t; i < MAXBK; i += 256) h[i] = 0;
  __syncthreads();
  int e0 = blockIdx.x * PCH;
  #pragma unroll
  for (int j = 0; j < PCH / 256; j++){
    int e = e0 + t + j * 256;
    if (e < E) atomicAdd(&h[dst[e] >> BKSHIFT], 1);
  }
  __syncthreads();
  for (int i = t; i < MAXBK; i += 256) if (h[i]) atomicAdd(&bcnt[i], h[i]);
}

// B) scan bucket counts -> bOff[nbk+1], bCur; also row_ptr[N]=E
__global__ __launch_bounds__(256) void k_bscan(const int* __restrict__ bcnt,
    int* __restrict__ bOff, int* __restrict__ bCur, int* __restrict__ row_ptr,
    int nbk, int N, int E){
  __shared__ int sh[256];
  int t = threadIdx.x;
  int v = (t < nbk) ? bcnt[t] : 0;
  sh[t] = v; __syncthreads();
  for (int off = 1; off < 256; off <<= 1){
    int x = (t >= off) ? sh[t - off] : 0;
    __syncthreads();
    sh[t] += x;
    __syncthreads();
  }
  if (t < nbk){ int ex = sh[t] - v; bOff[t] = ex; bCur[t] = ex; }
  if (t == 0){ bOff[nbk] = E; row_ptr[N] = E; }
}

// C) partition edges into bucket-grouped epart[] with LDS-staged coalesced writes
__global__ __launch_bounds__(256) void k_part(const int* __restrict__ src,
    const int* __restrict__ dst, int* __restrict__ bCur,
    uint2* __restrict__ epart, int E){
  __shared__ int scnt[MAXBK], soff[MAXBK], sbase[MAXBK], scur[MAXBK];
  __shared__ int stmp[256];
  __shared__ uint2 stage[PCH];   // 32 KB
  int t = threadIdx.x;
  int e0 = blockIdx.x * PCH;
  int eN = E - e0; if (eN > PCH) eN = PCH;
  for (int i = t; i < MAXBK; i += 256){ scnt[i] = 0; scur[i] = 0; }
  __syncthreads();
  uint2 mye[PCH / 256];
  #pragma unroll
  for (int j = 0; j < PCH / 256; j++){
    int e = e0 + t + j * 256;
    if (e < E){
      mye[j].x = (unsigned)src[e];
      mye[j].y = (unsigned)dst[e];
      atomicAdd(&scnt[mye[j].y >> BKSHIFT], 1);
    }
  }
  __syncthreads();
  // exclusive scan of scnt (256 == MAXBK lanes)
  int v = scnt[t];
  stmp[t] = v; __syncthreads();
  for (int off = 1; off < 256; off <<= 1){
    int x = (t >= off) ? stmp[t - off] : 0;
    __syncthreads();
    stmp[t] += x;
    __syncthreads();
  }
  soff[t] = stmp[t] - v;
  // reserve this block's run in each bucket
  if (v > 0) sbase[t] = atomicAdd(&bCur[t], v);
  __syncthreads();
  // place edges into stage, grouped by bucket
  #pragma unroll
  for (int j = 0; j < PCH / 256; j++){
    int e = e0 + t + j * 256;
    if (e < E){
      int b = mye[j].y >> BKSHIFT;
      int l = atomicAdd(&scur[b], 1);
      stage[soff[b] + l] = mye[j];
    }
  }
  __syncthreads();
  // write out: consecutive threads -> consecutive slots within per-bucket runs
  for (int j = t; j < eN; j += 256){
    uint2 ed = stage[j];
    int b = (int)(ed.y >> BKSHIFT);
    epart[(size_t)sbase[b] + (j - soff[b])] = ed;
  }
}

// D) per-bucket CSR build: row_ptr, col, dinv — all state in LDS, confined writes
__global__ __launch_bounds__(256) void k_bfill(const uint2* __restrict__ epart,
    const int* __restrict__ bOff, int* __restrict__ row_ptr,
    int* __restrict__ col, float* __restrict__ dinv, int N){
  __shared__ int hc[BKNODES], off[BKNODES], cur[BKNODES];
  __shared__ int stmp[256];
  int b = blockIdx.x, t = threadIdx.x;
  int base = bOff[b], cntE = bOff[b + 1] - base;
  int node0 = b << BKSHIFT;
  int nloc = N - node0; if (nloc > BKNODES) nloc = BKNODES;
  for (int i = t; i < BKNODES; i += 256) hc[i] = 0;
  __syncthreads();
  for (int j = t; j < cntE; j += 256){
    uint2 ed = epart[(size_t)base + j];
    atomicAdd(&hc[ed.y - node0], 1);
  }
  __syncthreads();
  // exclusive scan of 512 via pairs on 256 threads
  int a0 = hc[2 * t], a1 = hc[2 * t + 1];
  int s = a0 + a1;
  stmp[t] = s; __syncthreads();
  for (int o = 1; o < 256; o <<= 1){
    int x = (t >= o) ? stmp[t - o] : 0;
    __syncthreads();
    stmp[t] += x;
    __syncthreads();
  }
  int ex = stmp[t] - s;
  off[2 * t] = ex; off[2 * t + 1] = ex + a0;
  __syncthreads();
  for (int i = t; i < nloc; i += 256){
    row_ptr[node0 + i] = base + off[i];
    dinv[node0 + i]    = rsqrtf((float)hc[i] + 1.0f);
    cur[i] = off[i];
  }
  __syncthreads();
  for (int j = t; j < cntE; j += 256){
    uint2 ed = epart[(size_t)base + j];
    int p = atomicAdd(&cur[ed.y - node0], 1);
    col[base + p] = (int)ed.x;
  }
}

// E) fp32 -> fp16 convert (x -> xh), 8 elems/thread
__global__ __launch_bounds__(256) void k_cvt(const float* __restrict__ in,
    _Float16* __restrict__ outp, int n8){
  int i = blockIdx.x * 256 + threadIdx.x;
  if (i >= n8) return;
  float4 a = *(const float4*)&in[(size_t)i * 8];
  float4 b = *(const float4*)&in[(size_t)i * 8 + 4];
  __half2 p0 = __floats2half2_rn(a.x, a.y);
  __half2 p1 = __floats2half2_rn(a.z, a.w);
  __half2 p2 = __floats2half2_rn(b.x, b.y);
  __half2 p3 = __floats2half2_rn(b.z, b.w);
  uint4 u;
  u.x = *(unsigned*)&p0; u.y = *(unsigned*)&p1;
  u.z = *(unsigned*)&p2; u.w = *(unsigned*)&p3;
  *(uint4*)&outp[(size_t)i * 8] = u;
}

// F) convert W0/W1/W2 (fp32, row-major [k][n], 128x128) into fp16 MFMA B-frag
//    swizzle: Wsw[layer][((k0*8 + t)*64 + lane)*8 + j] = W[k0*32 + quad*8 + j][16t + n15]
__global__ __launch_bounds__(256) void k_wcvt3(const float* __restrict__ W0,
    const float* __restrict__ W1, const float* __restrict__ W2,
    _Float16* __restrict__ Wsw){
  const float* W = (blockIdx.x == 0) ? W0 : (blockIdx.x == 1) ? W1 : W2;
  _Float16* dst = Wsw + (size_t)blockIdx.x * 16384;
  int lane = threadIdx.x & 63;
  int quad = lane >> 4;
  int n    = lane & 15;
  for (int pair = (threadIdx.x >> 6); pair < 32; pair += 4){
    int k0 = pair >> 3;
    int tt = pair & 7;
    _Float16 v[8];
    #pragma unroll
    for (int j = 0; j < 8; j++){
      int k = k0 * 32 + quad * 8 + j;
      v[j] = (_Float16)W[k * 128 + 16 * tt + n];
    }
    *(uint4*)&dst[((size_t)pair * 64 + lane) * 8] = *(uint4*)v;
  }
}

// 5) MFMA GEMM: C[M,128] = A[M,128] @ W[128,128]; fp16 in/out, fp32 accum.
//    One wave per 16-row strip; B-frags from pre-swizzled global (L1-hot);
//    per-wave LDS transpose epilogue (pad 136 to dodge bank conflicts).
__global__ __launch_bounds__(256) void gemm_mfma(const _Float16* __restrict__ A,
    const _Float16* __restrict__ Wsw, _Float16* __restrict__ C, int M){
  __shared__ _Float16 lds[4][16][136];   // 17.4 KB
  int wave = threadIdx.x >> 6;
  int lane = threadIdx.x & 63;
  int quad = lane >> 4;
  int l15  = lane & 15;
  int m0 = blockIdx.x * 64 + wave * 16;
  if (m0 >= M) return;                   // no cross-wave sync used
  f4 acc[8] = {};
  h8 af[4];
  const _Float16* arow = A + (size_t)(m0 + l15) * D;
  #pragma unroll
  for (int k0 = 0; k0 < 4; k0++)
    af[k0] = *(const h8*)&arow[k0 * 32 + quad * 8];
  #pragma unroll
  for (int k0 = 0; k0 < 4; k0++){
    #pragma unroll
    for (int t = 0; t < 8; t++){
      h8 bf = *(const h8*)&Wsw[((size_t)(k0 * 8 + t) * 64 + lane) * 8];
      acc[t] = __builtin_amdgcn_mfma_f32_16x16x32_f16(af[k0], bf, acc[t], 0, 0, 0);
    }
  }
  // C/D layout: col = lane&15, row = quad*4 + r  -> LDS (row, col)
  #pragma unroll
  for (int t = 0; t < 8; t++){
    #pragma unroll
    for (int r = 0; r < 4; r++)
      lds[wave][quad * 4 + r][t * 16 + l15] = (_Float16)acc[t][r];
  }
  // read back coalesced: 256 chunks of 8 halves; 4 per lane
  #pragma unroll
  for (int it = 0; it < 4; it++){
    int idx = it * 64 + lane;
    int row = idx >> 4;
    int ch  = idx & 15;
    *(uint4*)&C[(size_t)(m0 + row) * D + ch * 8] = *(uint4*)&lds[wave][row][ch * 8];
  }
}

// accumulate 8 halves * w into acc[8]; (float)h * w + acc -> v_fma_mix_f32
__device__ __forceinline__ void accm(float* acc, uint4 u, float w){
  union { uint4 u; _Float16 h[8]; } cv;
  cv.u = u;
  #pragma unroll
  for (int k = 0; k < 8; k++)
    acc[k] += (float)cv.h[k] * w;
}

// 6) CSR aggregation: one wave per node, 4 gather chains/lane, fp16 in/out.
__global__ __launch_bounds__(256) void k_agg(const __half* __restrict__ t,
    const int* __restrict__ row_ptr, const int* __restrict__ col,
    const float* __restrict__ dinv, const float* __restrict__ bias,
    __half* __restrict__ outh, int relu, int N){
  int node = blockIdx.x * 4 + (threadIdx.x >> 6);
  if (node >= N) return;
  int lane = threadIdx.x & 63;
  int way  = lane >> 4;          // 0..3
  int cg   = (lane & 15) * 8;    // first col of this lane's 8-half group
  float di = dinv[node];
  int beg = row_ptr[node], end = row_ptr[node + 1];
  float acc[8] = {0.f,0.f,0.f,0.f,0.f,0.f,0.f,0.f};
  int j = beg + way;
  for (; j + 12 < end; j += 16){
    int s0 = col[j], s1 = col[j + 4], s2 = col[j + 8], s3 = col[j + 12];
    float w0 = dinv[s0] * di;
    float w1 = dinv[s1] * di;
    float w2 = dinv[s2] * di;
    float w3 = dinv[s3] * di;
    uint4 u0 = *(const uint4*)&t[(size_t)s0 * D + cg];
    uint4 u1 = *(const uint4*)&t[(size_t)s1 * D + cg];
    uint4 u2 = *(const uint4*)&t[(size_t)s2 * D + cg];
    uint4 u3 = *(const uint4*)&t[(size_t)s3 * D + cg];
    accm(acc, u0, w0);
    accm(acc, u1, w1);
    accm(acc, u2, w2);
    accm(acc, u3, w3);
  }
  for (; j < end; j += 4){
    int s = col[j];
    float w = dinv[s] * di;
    uint4 u = *(const uint4*)&t[(size_t)s * D + cg];
    accm(acc, u, w);
  }
  #pragma unroll
  for (int k = 0; k < 8; k++){
    acc[k] += __shfl_xor(acc[k], 16, 64);
    acc[k] += __shfl_xor(acc[k], 32, 64);
  }
  if (way == 0){
    uint4 su = *(const uint4*)&t[(size_t)node * D + cg];
    union { uint4 u; _Float16 h[8]; } sv; sv.u = su;
    float dii = di * di;
    float4 b0 = *(const float4*)&bias[cg];
    float4 b1 = *(const float4*)&bias[cg + 4];
    float bb[8] = {b0.x, b0.y, b0.z, b0.w, b1.x, b1.y, b1.z, b1.w};
    float o[8];
    #pragma unroll
    for (int k = 0; k < 8; k++)
      o[k] = acc[k] + (float)sv.h[k] * dii + bb[k];
    if (relu){
      #pragma unroll
      for (int k = 0; k < 8; k++) o[k] = fmaxf(o[k], 0.f);
    }
    __half2 p0 = __floats2half2_rn(o[0], o[1]);
    __half2 p1 = __floats2half2_rn(o[2], o[3]);
    __half2 p2 = __floats2half2_rn(o[4], o[5]);
    __half2 p3 = __floats2half2_rn(o[6], o[7]);
    uint4 u;
    u.x = *(unsigned*)&p0; u.y = *(unsigned*)&p1;
    u.z = *(unsigned*)&p2; u.w = *(unsigned*)&p3;
    *(uint4*)&outh[(size_t)node * D + cg] = u;
  }
}

// 7) chunked segment-max (fp16 input) into ordered-uint atomicMax (batch sorted)
__global__ __launch_bounds__(128) void k_pool(const __half* __restrict__ h,
    const int* __restrict__ batch, unsigned* __restrict__ pk, int N){
  int d = threadIdx.x;
  int n0 = blockIdx.x * 128;
  int nEnd = n0 + 128; if (nEnd > N) nEnd = N;
  float cur = -FLT_MAX;
  int curg = batch[n0];
  for (int n = n0; n < nEnd; n++){
    int g = batch[n];
    if (g != curg){
      atomicMax(&pk[curg * D + d], fkey(cur));
      cur = -FLT_MAX; curg = g;
    }
    cur = fmaxf(cur, __half2float(h[(size_t)n * D + d]));
  }
  atomicMax(&pk[curg * D + d], fkey(cur));
}

// 8) final: out[64,2] = pooled @ Wf + bf
__global__ __launch_bounds__(128) void k_final(const unsigned* __restrict__ pk,
    const float* __restrict__ Wf, const float* __restrict__ bf,
    float* __restrict__ out){
  int t = threadIdx.x;
  int g = t >> 1, c = t & 1;
  float s = bf[c];
  for (int k = 0; k < D; k++)
    s += funkey(pk[g * D + k]) * Wf[k * 2 + c];
  out[g * 2 + c] = s;
}

extern "C" void kernel_launch(void* const* d_in, const int* in_sizes, int n_in,
                              void* d_out, int out_size, void* d_ws, size_t ws_size,
                              hipStream_t stream){
  const float* x   = (const float*)d_in[0];
  const int*   ei  = (const int*)d_in[1];
  const int*   bat = (const int*)d_in[2];
  const float* W0  = (const float*)d_in[3];
  const float* b0  = (const float*)d_in[4];
  const float* W1  = (const float*)d_in[5];
  const float* b1  = (const float*)d_in[6];
  const float* W2  = (const float*)d_in[7];
  const float* b2  = (const float*)d_in[8];
  const float* Wf  = (const float*)d_in[9];
  const float* bf  = (const float*)d_in[10];
  int N = in_sizes[0] / D;
  int E = in_sizes[1] / 2;
  const int* srcp = ei;
  const int* dstp = ei + E;
  int nbk   = (N + BKNODES - 1) / BKNODES;
  int npart = (E + PCH - 1) / PCH;

  char* p = (char*)d_ws;
  auto alloc = [&](size_t bytes)->char*{
    char* r = p; p += (bytes + 255) & ~(size_t)255; return r;
  };
  float*     dinv    = (float*)alloc((size_t)N * 4);
  int*       row_ptr = (int*)alloc((size_t)(N + 1) * 4);
  int*       col     = (int*)alloc((size_t)E * 4);
  uint2*     epart   = (uint2*)alloc((size_t)E * 8);
  _Float16*  tmp     = (_Float16*)alloc((size_t)N * D * 2);  // gemm out
  _Float16*  h16     = (_Float16*)alloc((size_t)N * D * 2);  // xh / agg out
  _Float16*  Wsw     = (_Float16*)alloc((size_t)3 * 16384 * 2);
  unsigned*  pk      = (unsigned*)alloc((size_t)NGRAPHS * D * 4);
  int*       bcnt    = (int*)alloc((size_t)MAXBK * 4);
  int*       bOff    = (int*)alloc((size_t)(MAXBK + 1) * 4);
  int*       bCur    = (int*)alloc((size_t)MAXBK * 4);

  hipMemsetAsync(bcnt, 0, (size_t)MAXBK * 4, stream);
  hipMemsetAsync(pk, 0, (size_t)NGRAPHS * D * 4, stream);

  // x -> fp16 (h16 doubles as xh); W -> fp16 B-frag swizzle
  int n8 = N * D / 8;
  k_cvt<<<(n8 + 255) / 256, 256, 0, stream>>>(x, h16, n8);
  k_wcvt3<<<3, 256, 0, stream>>>(W0, W1, W2, Wsw);

  k_bhist<<<npart, 256, 0, stream>>>(dstp, bcnt, E);
  k_bscan<<<1, 256, 0, stream>>>(bcnt, bOff, bCur, row_ptr, nbk, N, E);
  k_part<<<npart, 256, 0, stream>>>(srcp, dstp, bCur, epart, E);
  k_bfill<<<nbk, 256, 0, stream>>>(epart, bOff, row_ptr, col, dinv, N);

  int gblocks = (N + 63) / 64;
  int ablocks = (N + 3) / 4;
  // layer 0
  gemm_mfma<<<gblocks, 256, 0, stream>>>(h16, Wsw, tmp, N);
  k_agg<<<ablocks, 256, 0, stream>>>((const __half*)tmp, row_ptr, col, dinv, b0, (__half*)h16, 1, N);
  // layer 1
  gemm_mfma<<<gblocks, 256, 0, stream>>>(h16, Wsw + 16384, tmp, N);
  k_agg<<<ablocks, 256, 0, stream>>>((const __half*)tmp, row_ptr, col, dinv, b1, (__half*)h16, 1, N);
  // layer 2 (no relu)
  gemm_mfma<<<gblocks, 256, 0, stream>>>(h16, Wsw + 32768, tmp, N);
  k_agg<<<ablocks, 256, 0, stream>>>((const __half*)tmp, row_ptr, col, dinv, b2, (__half*)h16, 0, N);
  // pool + classifier
  k_pool<<<(N + 127) / 128, 128, 0, stream>>>((const __half*)h16, bat, pk, N);
  k_final<<<1, 128, 0, stream>>>(pk, Wf, bf, (float*)d_out);
}

// Round 9
// 412.522 us; speedup vs baseline: 1.3244x; 1.0915x over previous
//
#include <hip/hip_runtime.h>
#include <hip/hip_bf16.h>
#include <hip/hip_fp16.h>
#include <float.h>

#define D 128
#define NGRAPHS 64
#define BKSHIFT 9
#define BKNODES 512     // nodes per bucket
#define MAXBK 256       // max buckets (N<=131072)
#define PCH 4096        // edges per partition block (256 thr x 16)

typedef _Float16 h8 __attribute__((ext_vector_type(8)));
typedef float f4 __attribute__((ext_vector_type(4)));

// ---- ordered-float encoding for atomicMax on unsigned ----
__device__ __forceinline__ unsigned fkey(float f){
  unsigned u = __float_as_uint(f);
  return (u & 0x80000000u) ? ~u : (u | 0x80000000u);
}
__device__ __forceinline__ float funkey(unsigned k){
  unsigned u = (k & 0x80000000u) ? (k ^ 0x80000000u) : ~k;
  return __uint_as_float(u);
}

// A) bucket histogram (blocks < npart) + W->fp16 B-frag swizzle (blocks npart..npart+2)
__global__ __launch_bounds__(256) void k_bhist_w(const int* __restrict__ dst,
    int* __restrict__ bcnt, int E, int npart,
    const float* __restrict__ W0, const float* __restrict__ W1,
    const float* __restrict__ W2, _Float16* __restrict__ Wsw){
  if ((int)blockIdx.x >= npart){
    int layer = blockIdx.x - npart;
    const float* W = (layer == 0) ? W0 : (layer == 1) ? W1 : W2;
    _Float16* dstp = Wsw + (size_t)layer * 16384;
    int lane = threadIdx.x & 63;
    int quad = lane >> 4;
    int n    = lane & 15;
    for (int pair = (threadIdx.x >> 6); pair < 32; pair += 4){
      int k0 = pair >> 3;
      int tt = pair & 7;
      _Float16 v[8];
      #pragma unroll
      for (int j = 0; j < 8; j++){
        int k = k0 * 32 + quad * 8 + j;
        v[j] = (_Float16)W[k * 128 + 16 * tt + n];
      }
      *(uint4*)&dstp[((size_t)pair * 64 + lane) * 8] = *(uint4*)v;
    }
    return;
  }
  __shared__ int h[MAXBK];
  int t = threadIdx.x;
  for (int i = t; i < MAXBK; i += 256) h[i] = 0;
  __syncthreads();
  int e0 = blockIdx.x * PCH;
  #pragma unroll
  for (int j = 0; j < PCH / 256; j++){
    int e = e0 + t + j * 256;
    if (e < E) atomicAdd(&h[dst[e] >> BKSHIFT], 1);
  }
  __syncthreads();
  for (int i = t; i < MAXBK; i += 256) if (h[i]) atomicAdd(&bcnt[i], h[i]);
}

// B) scan bucket counts -> bOff[nbk+1], bCur; row_ptr[N]=E; zero pk
__global__ __launch_bounds__(256) void k_bscan(const int* __restrict__ bcnt,
    int* __restrict__ bOff, int* __restrict__ bCur, int* __restrict__ row_ptr,
    unsigned* __restrict__ pk, int nbk, int N, int E){
  __shared__ int sh[256];
  int t = threadIdx.x;
  for (int i = t; i < NGRAPHS * D; i += 256) pk[i] = 0u;
  int v = (t < nbk) ? bcnt[t] : 0;
  sh[t] = v; __syncthreads();
  for (int off = 1; off < 256; off <<= 1){
    int x = (t >= off) ? sh[t - off] : 0;
    __syncthreads();
    sh[t] += x;
    __syncthreads();
  }
  if (t < nbk){ int ex = sh[t] - v; bOff[t] = ex; bCur[t] = ex; }
  if (t == 0){ bOff[nbk] = E; row_ptr[N] = E; }
}

// C) partition edges into bucket-grouped epart[] with LDS-staged coalesced writes
__global__ __launch_bounds__(256) void k_part(const int* __restrict__ src,
    const int* __restrict__ dst, int* __restrict__ bCur,
    uint2* __restrict__ epart, int E){
  __shared__ int scnt[MAXBK], soff[MAXBK], sbase[MAXBK], scur[MAXBK];
  __shared__ int stmp[256];
  __shared__ uint2 stage[PCH];   // 32 KB
  int t = threadIdx.x;
  int e0 = blockIdx.x * PCH;
  int eN = E - e0; if (eN > PCH) eN = PCH;
  for (int i = t; i < MAXBK; i += 256){ scnt[i] = 0; scur[i] = 0; }
  __syncthreads();
  uint2 mye[PCH / 256];
  #pragma unroll
  for (int j = 0; j < PCH / 256; j++){
    int e = e0 + t + j * 256;
    if (e < E){
      mye[j].x = (unsigned)src[e];
      mye[j].y = (unsigned)dst[e];
      atomicAdd(&scnt[mye[j].y >> BKSHIFT], 1);
    }
  }
  __syncthreads();
  // exclusive scan of scnt (256 == MAXBK lanes)
  int v = scnt[t];
  stmp[t] = v; __syncthreads();
  for (int off = 1; off < 256; off <<= 1){
    int x = (t >= off) ? stmp[t - off] : 0;
    __syncthreads();
    stmp[t] += x;
    __syncthreads();
  }
  soff[t] = stmp[t] - v;
  // reserve this block's run in each bucket
  if (v > 0) sbase[t] = atomicAdd(&bCur[t], v);
  __syncthreads();
  // place edges into stage, grouped by bucket
  #pragma unroll
  for (int j = 0; j < PCH / 256; j++){
    int e = e0 + t + j * 256;
    if (e < E){
      int b = mye[j].y >> BKSHIFT;
      int l = atomicAdd(&scur[b], 1);
      stage[soff[b] + l] = mye[j];
    }
  }
  __syncthreads();
  // write out: consecutive threads -> consecutive slots within per-bucket runs
  for (int j = t; j < eN; j += 256){
    uint2 ed = stage[j];
    int b = (int)(ed.y >> BKSHIFT);
    epart[(size_t)sbase[b] + (j - soff[b])] = ed;
  }
}

// D) per-bucket CSR build: row_ptr, col, dinv — all state in LDS, confined writes
__global__ __launch_bounds__(256) void k_bfill(const uint2* __restrict__ epart,
    const int* __restrict__ bOff, int* __restrict__ row_ptr,
    int* __restrict__ col, float* __restrict__ dinv, int N){
  __shared__ int hc[BKNODES], off[BKNODES], cur[BKNODES];
  __shared__ int stmp[256];
  int b = blockIdx.x, t = threadIdx.x;
  int base = bOff[b], cntE = bOff[b + 1] - base;
  int node0 = b << BKSHIFT;
  int nloc = N - node0; if (nloc > BKNODES) nloc = BKNODES;
  for (int i = t; i < BKNODES; i += 256) hc[i] = 0;
  __syncthreads();
  for (int j = t; j < cntE; j += 256){
    uint2 ed = epart[(size_t)base + j];
    atomicAdd(&hc[ed.y - node0], 1);
  }
  __syncthreads();
  // exclusive scan of 512 via pairs on 256 threads
  int a0 = hc[2 * t], a1 = hc[2 * t + 1];
  int s = a0 + a1;
  stmp[t] = s; __syncthreads();
  for (int o = 1; o < 256; o <<= 1){
    int x = (t >= o) ? stmp[t - o] : 0;
    __syncthreads();
    stmp[t] += x;
    __syncthreads();
  }
  int ex = stmp[t] - s;
  off[2 * t] = ex; off[2 * t + 1] = ex + a0;
  __syncthreads();
  for (int i = t; i < nloc; i += 256){
    row_ptr[node0 + i] = base + off[i];
    dinv[node0 + i]    = rsqrtf((float)hc[i] + 1.0f);
    cur[i] = off[i];
  }
  __syncthreads();
  for (int j = t; j < cntE; j += 256){
    uint2 ed = epart[(size_t)base + j];
    int p = atomicAdd(&cur[ed.y - node0], 1);
    col[base + p] = (int)ed.x;
  }
}

// 5a) MFMA GEMM, fp16 A: C[M,128] = A[M,128] @ W[128,128]; fp32 accum, fp16 out.
__global__ __launch_bounds__(256) void gemm_mfma(const _Float16* __restrict__ A,
    const _Float16* __restrict__ Wsw, _Float16* __restrict__ C, int M){
  __shared__ _Float16 lds[4][16][136];   // 17.4 KB
  int wave = threadIdx.x >> 6;
  int lane = threadIdx.x & 63;
  int quad = lane >> 4;
  int l15  = lane & 15;
  int m0 = blockIdx.x * 64 + wave * 16;
  if (m0 >= M) return;                   // no cross-wave sync used
  f4 acc[8] = {};
  h8 af[4];
  const _Float16* arow = A + (size_t)(m0 + l15) * D;
  #pragma unroll
  for (int k0 = 0; k0 < 4; k0++)
    af[k0] = *(const h8*)&arow[k0 * 32 + quad * 8];
  #pragma unroll
  for (int k0 = 0; k0 < 4; k0++){
    #pragma unroll
    for (int t = 0; t < 8; t++){
      h8 bf = *(const h8*)&Wsw[((size_t)(k0 * 8 + t) * 64 + lane) * 8];
      acc[t] = __builtin_amdgcn_mfma_f32_16x16x32_f16(af[k0], bf, acc[t], 0, 0, 0);
    }
  }
  #pragma unroll
  for (int t = 0; t < 8; t++){
    #pragma unroll
    for (int r = 0; r < 4; r++)
      lds[wave][quad * 4 + r][t * 16 + l15] = (_Float16)acc[t][r];
  }
  #pragma unroll
  for (int it = 0; it < 4; it++){
    int idx = it * 64 + lane;
    int row = idx >> 4;
    int ch  = idx & 15;
    *(uint4*)&C[(size_t)(m0 + row) * D + ch * 8] = *(uint4*)&lds[wave][row][ch * 8];
  }
}

// 5b) MFMA GEMM, fp32 A (layer 0): reads x directly, cvt in-register.
__global__ __launch_bounds__(256) void gemm_mfma_f32A(const float* __restrict__ A,
    const _Float16* __restrict__ Wsw, _Float16* __restrict__ C, int M){
  __shared__ _Float16 lds[4][16][136];
  int wave = threadIdx.x >> 6;
  int lane = threadIdx.x & 63;
  int quad = lane >> 4;
  int l15  = lane & 15;
  int m0 = blockIdx.x * 64 + wave * 16;
  if (m0 >= M) return;
  f4 acc[8] = {};
  h8 af[4];
  const float* arow = A + (size_t)(m0 + l15) * D;
  #pragma unroll
  for (int k0 = 0; k0 < 4; k0++){
    float4 a = *(const float4*)&arow[k0 * 32 + quad * 8];
    float4 b = *(const float4*)&arow[k0 * 32 + quad * 8 + 4];
    __half2 p0 = __floats2half2_rn(a.x, a.y);
    __half2 p1 = __floats2half2_rn(a.z, a.w);
    __half2 p2 = __floats2half2_rn(b.x, b.y);
    __half2 p3 = __floats2half2_rn(b.z, b.w);
    union { uint4 u; h8 v; } cv;
    cv.u.x = *(unsigned*)&p0; cv.u.y = *(unsigned*)&p1;
    cv.u.z = *(unsigned*)&p2; cv.u.w = *(unsigned*)&p3;
    af[k0] = cv.v;
  }
  #pragma unroll
  for (int k0 = 0; k0 < 4; k0++){
    #pragma unroll
    for (int t = 0; t < 8; t++){
      h8 bf = *(const h8*)&Wsw[((size_t)(k0 * 8 + t) * 64 + lane) * 8];
      acc[t] = __builtin_amdgcn_mfma_f32_16x16x32_f16(af[k0], bf, acc[t], 0, 0, 0);
    }
  }
  #pragma unroll
  for (int t = 0; t < 8; t++){
    #pragma unroll
    for (int r = 0; r < 4; r++)
      lds[wave][quad * 4 + r][t * 16 + l15] = (_Float16)acc[t][r];
  }
  #pragma unroll
  for (int it = 0; it < 4; it++){
    int idx = it * 64 + lane;
    int row = idx >> 4;
    int ch  = idx & 15;
    *(uint4*)&C[(size_t)(m0 + row) * D + ch * 8] = *(uint4*)&lds[wave][row][ch * 8];
  }
}

// accumulate 8 halves * w into acc[8]; (float)h * w + acc -> v_fma_mix_f32
__device__ __forceinline__ void accm(float* acc, uint4 u, float w){
  union { uint4 u; _Float16 h[8]; } cv;
  cv.u = u;
  #pragma unroll
  for (int k = 0; k < 8; k++)
    acc[k] += (float)cv.h[k] * w;
}

// 6) CSR aggregation: one wave per node, 4 gather chains/lane, fp16 in/out.
__global__ __launch_bounds__(256) void k_agg(const __half* __restrict__ t,
    const int* __restrict__ row_ptr, const int* __restrict__ col,
    const float* __restrict__ dinv, const float* __restrict__ bias,
    __half* __restrict__ outh, int relu, int N){
  int node = blockIdx.x * 4 + (threadIdx.x >> 6);
  if (node >= N) return;
  int lane = threadIdx.x & 63;
  int way  = lane >> 4;          // 0..3
  int cg   = (lane & 15) * 8;    // first col of this lane's 8-half group
  float di = dinv[node];
  int beg = row_ptr[node], end = row_ptr[node + 1];
  float acc[8] = {0.f,0.f,0.f,0.f,0.f,0.f,0.f,0.f};
  int j = beg + way;
  for (; j + 12 < end; j += 16){
    int s0 = col[j], s1 = col[j + 4], s2 = col[j + 8], s3 = col[j + 12];
    float w0 = dinv[s0] * di;
    float w1 = dinv[s1] * di;
    float w2 = dinv[s2] * di;
    float w3 = dinv[s3] * di;
    uint4 u0 = *(const uint4*)&t[(size_t)s0 * D + cg];
    uint4 u1 = *(const uint4*)&t[(size_t)s1 * D + cg];
    uint4 u2 = *(const uint4*)&t[(size_t)s2 * D + cg];
    uint4 u3 = *(const uint4*)&t[(size_t)s3 * D + cg];
    accm(acc, u0, w0);
    accm(acc, u1, w1);
    accm(acc, u2, w2);
    accm(acc, u3, w3);
  }
  for (; j < end; j += 4){
    int s = col[j];
    float w = dinv[s] * di;
    uint4 u = *(const uint4*)&t[(size_t)s * D + cg];
    accm(acc, u, w);
  }
  #pragma unroll
  for (int k = 0; k < 8; k++){
    acc[k] += __shfl_xor(acc[k], 16, 64);
    acc[k] += __shfl_xor(acc[k], 32, 64);
  }
  if (way == 0){
    uint4 su = *(const uint4*)&t[(size_t)node * D + cg];
    union { uint4 u; _Float16 h[8]; } sv; sv.u = su;
    float dii = di * di;
    float4 b0 = *(const float4*)&bias[cg];
    float4 b1 = *(const float4*)&bias[cg + 4];
    float bb[8] = {b0.x, b0.y, b0.z, b0.w, b1.x, b1.y, b1.z, b1.w};
    float o[8];
    #pragma unroll
    for (int k = 0; k < 8; k++)
      o[k] = acc[k] + (float)sv.h[k] * dii + bb[k];
    if (relu){
      #pragma unroll
      for (int k = 0; k < 8; k++) o[k] = fmaxf(o[k], 0.f);
    }
    __half2 p0 = __floats2half2_rn(o[0], o[1]);
    __half2 p1 = __floats2half2_rn(o[2], o[3]);
    __half2 p2 = __floats2half2_rn(o[4], o[5]);
    __half2 p3 = __floats2half2_rn(o[6], o[7]);
    uint4 u;
    u.x = *(unsigned*)&p0; u.y = *(unsigned*)&p1;
    u.z = *(unsigned*)&p2; u.w = *(unsigned*)&p3;
    *(uint4*)&outh[(size_t)node * D + cg] = u;
  }
}

// 7) chunked segment-max (fp16 input), 64-row chunks, 4-deep load batching.
__global__ __launch_bounds__(128) void k_pool(const __half* __restrict__ h,
    const int* __restrict__ batch, unsigned* __restrict__ pk, int N){
  int d = threadIdx.x;
  int n0 = blockIdx.x * 64;
  int nEnd = n0 + 64; if (nEnd > N) nEnd = N;
  float cur = -FLT_MAX;
  int curg = batch[n0];
  int n = n0;
  for (; n + 3 < nEnd; n += 4){
    const __half* r = &h[(size_t)n * D + d];
    __half v0 = r[0], v1 = r[D], v2 = r[2 * D], v3 = r[3 * D];
    int g0 = batch[n], g1 = batch[n + 1], g2 = batch[n + 2], g3 = batch[n + 3];
    if (g0 != curg){ atomicMax(&pk[curg * D + d], fkey(cur)); cur = -FLT_MAX; curg = g0; }
    cur = fmaxf(cur, __half2float(v0));
    if (g1 != curg){ atomicMax(&pk[curg * D + d], fkey(cur)); cur = -FLT_MAX; curg = g1; }
    cur = fmaxf(cur, __half2float(v1));
    if (g2 != curg){ atomicMax(&pk[curg * D + d], fkey(cur)); cur = -FLT_MAX; curg = g2; }
    cur = fmaxf(cur, __half2float(v2));
    if (g3 != curg){ atomicMax(&pk[curg * D + d], fkey(cur)); cur = -FLT_MAX; curg = g3; }
    cur = fmaxf(cur, __half2float(v3));
  }
  for (; n < nEnd; n++){
    int g = batch[n];
    if (g != curg){ atomicMax(&pk[curg * D + d], fkey(cur)); cur = -FLT_MAX; curg = g; }
    cur = fmaxf(cur, __half2float(h[(size_t)n * D + d]));
  }
  atomicMax(&pk[curg * D + d], fkey(cur));
}

// 8) final: out[64,2] = pooled @ Wf + bf
__global__ __launch_bounds__(128) void k_final(const unsigned* __restrict__ pk,
    const float* __restrict__ Wf, const float* __restrict__ bf,
    float* __restrict__ out){
  int t = threadIdx.x;
  int g = t >> 1, c = t & 1;
  float s = bf[c];
  for (int k = 0; k < D; k++)
    s += funkey(pk[g * D + k]) * Wf[k * 2 + c];
  out[g * 2 + c] = s;
}

extern "C" void kernel_launch(void* const* d_in, const int* in_sizes, int n_in,
                              void* d_out, int out_size, void* d_ws, size_t ws_size,
                              hipStream_t stream){
  const float* x   = (const float*)d_in[0];
  const int*   ei  = (const int*)d_in[1];
  const int*   bat = (const int*)d_in[2];
  const float* W0  = (const float*)d_in[3];
  const float* b0  = (const float*)d_in[4];
  const float* W1  = (const float*)d_in[5];
  const float* b1  = (const float*)d_in[6];
  const float* W2  = (const float*)d_in[7];
  const float* b2  = (const float*)d_in[8];
  const float* Wf  = (const float*)d_in[9];
  const float* bf  = (const float*)d_in[10];
  int N = in_sizes[0] / D;
  int E = in_sizes[1] / 2;
  const int* srcp = ei;
  const int* dstp = ei + E;
  int nbk   = (N + BKNODES - 1) / BKNODES;
  int npart = (E + PCH - 1) / PCH;

  char* p = (char*)d_ws;
  auto alloc = [&](size_t bytes)->char*{
    char* r = p; p += (bytes + 255) & ~(size_t)255; return r;
  };
  float*     dinv    = (float*)alloc((size_t)N * 4);
  int*       row_ptr = (int*)alloc((size_t)(N + 1) * 4);
  int*       col     = (int*)alloc((size_t)E * 4);
  uint2*     epart   = (uint2*)alloc((size_t)E * 8);
  _Float16*  tmp     = (_Float16*)alloc((size_t)N * D * 2);  // gemm out
  _Float16*  h16     = (_Float16*)alloc((size_t)N * D * 2);  // agg out
  _Float16*  Wsw     = (_Float16*)alloc((size_t)3 * 16384 * 2);
  unsigned*  pk      = (unsigned*)alloc((size_t)NGRAPHS * D * 4);
  int*       bcnt    = (int*)alloc((size_t)MAXBK * 4);
  int*       bOff    = (int*)alloc((size_t)(MAXBK + 1) * 4);
  int*       bCur    = (int*)alloc((size_t)MAXBK * 4);

  hipMemsetAsync(bcnt, 0, (size_t)MAXBK * 4, stream);

  // graph build + weight swizzle (fused) ; pk zeroed inside k_bscan
  k_bhist_w<<<npart + 3, 256, 0, stream>>>(dstp, bcnt, E, npart, W0, W1, W2, Wsw);
  k_bscan<<<1, 256, 0, stream>>>(bcnt, bOff, bCur, row_ptr, pk, nbk, N, E);
  k_part<<<npart, 256, 0, stream>>>(srcp, dstp, bCur, epart, E);
  k_bfill<<<nbk, 256, 0, stream>>>(epart, bOff, row_ptr, col, dinv, N);

  int gblocks = (N + 63) / 64;
  int ablocks = (N + 3) / 4;
  // layer 0 (reads fp32 x directly)
  gemm_mfma_f32A<<<gblocks, 256, 0, stream>>>(x, Wsw, tmp, N);
  k_agg<<<ablocks, 256, 0, stream>>>((const __half*)tmp, row_ptr, col, dinv, b0, (__half*)h16, 1, N);
  // layer 1
  gemm_mfma<<<gblocks, 256, 0, stream>>>(h16, Wsw + 16384, tmp, N);
  k_agg<<<ablocks, 256, 0, stream>>>((const __half*)tmp, row_ptr, col, dinv, b1, (__half*)h16, 1, N);
  // layer 2 (no relu)
  gemm_mfma<<<gblocks, 256, 0, stream>>>(h16, Wsw + 32768, tmp, N);
  k_agg<<<ablocks, 256, 0, stream>>>((const __half*)tmp, row_ptr, col, dinv, b2, (__half*)h16, 0, N);
  // pool + classifier
  k_pool<<<(N + 63) / 64, 128, 0, stream>>>((const __half*)h16, bat, pk, N);
  k_final<<<1, 128, 0, stream>>>(pk, Wf, bf, (float*)d_out);
}

// Round 10
// 409.030 us; speedup vs baseline: 1.3357x; 1.0085x over previous
//
#include <hip/hip_runtime.h>
#include <hip/hip_bf16.h>
#include <hip/hip_fp16.h>
#include <float.h>

#define D 128
#define NGRAPHS 64
#define BKSHIFT 9
#define BKNODES 512     // nodes per bucket
#define MAXBK 256       // max buckets (N<=131072)
#define PCH 4096        // edges per partition block (256 thr x 16)

typedef _Float16 h8 __attribute__((ext_vector_type(8)));
typedef float f4 __attribute__((ext_vector_type(4)));

// ---- ordered-float encoding for atomicMax on unsigned ----
__device__ __forceinline__ unsigned fkey(float f){
  unsigned u = __float_as_uint(f);
  return (u & 0x80000000u) ? ~u : (u | 0x80000000u);
}
__device__ __forceinline__ float funkey(unsigned k){
  unsigned u = (k & 0x80000000u) ? (k ^ 0x80000000u) : ~k;
  return __uint_as_float(u);
}

// ---- W fp32 row-major -> fp16 MFMA B-frag swizzle for one "pair" unit ----
// Wsw[((pair)*64 + lane)*8 + j] = W[(pair>>3)*32 + quad*8 + j][16*(pair&7) + (lane&15)]
__device__ __forceinline__ void wcvt_pair(const float* __restrict__ W,
    _Float16* __restrict__ dstp, int pair, int lane){
  int quad = lane >> 4;
  int n    = lane & 15;
  int k0 = pair >> 3;
  int tt = pair & 7;
  _Float16 v[8];
  #pragma unroll
  for (int j = 0; j < 8; j++){
    int k = k0 * 32 + quad * 8 + j;
    v[j] = (_Float16)W[k * 128 + 16 * tt + n];
  }
  *(uint4*)&dstp[((size_t)pair * 64 + lane) * 8] = *(uint4*)v;
}

// 0) W0 swizzle (8 blocks x 4 waves = 32 pairs) + zero bcnt
__global__ __launch_bounds__(256) void k_wcvt0(const float* __restrict__ W0,
    _Float16* __restrict__ Wsw, int* __restrict__ bcnt){
  if (blockIdx.x == 0 && threadIdx.x < MAXBK) bcnt[threadIdx.x] = 0;
  int lane = threadIdx.x & 63;
  int pair = blockIdx.x * 4 + (threadIdx.x >> 6);
  wcvt_pair(W0, Wsw, pair, lane);
}

// 1) MEGA: blocks [0,gb): gemm0 fp32-A MFMA; [gb,gb+npart): bucket histogram;
//    [gb+npart, +4): W1/W2 swizzle (2 blocks each, 16 pairs/block).
__global__ __launch_bounds__(256) void k_mega(
    const float* __restrict__ x, const _Float16* __restrict__ Wsw0,
    _Float16* __restrict__ C, int M, int gb,
    const int* __restrict__ dst, int* __restrict__ bcnt, int E, int npart,
    const float* __restrict__ W1, const float* __restrict__ W2,
    _Float16* __restrict__ Wsw12){
  __shared__ __align__(16) char smraw[4 * 16 * 136 * 2];  // 17.4 KB union
  int bid = blockIdx.x;
  if (bid < gb){
    // ---- gemm0: C[M,128] = cvt16(x[M,128]) @ W0 ----
    _Float16 (*lds)[136] = (_Float16(*)[136])(smraw + (threadIdx.x >> 6) * 16 * 136 * 2);
    int lane = threadIdx.x & 63;
    int quad = lane >> 4;
    int l15  = lane & 15;
    int m0 = bid * 64 + (threadIdx.x >> 6) * 16;
    if (m0 >= M) return;     // wave-level; no cross-wave sync in this path
    f4 acc[8] = {};
    h8 af[4];
    const float* arow = x + (size_t)(m0 + l15) * D;
    #pragma unroll
    for (int k0 = 0; k0 < 4; k0++){
      float4 a = *(const float4*)&arow[k0 * 32 + quad * 8];
      float4 b = *(const float4*)&arow[k0 * 32 + quad * 8 + 4];
      __half2 p0 = __floats2half2_rn(a.x, a.y);
      __half2 p1 = __floats2half2_rn(a.z, a.w);
      __half2 p2 = __floats2half2_rn(b.x, b.y);
      __half2 p3 = __floats2half2_rn(b.z, b.w);
      union { uint4 u; h8 v; } cv;
      cv.u.x = *(unsigned*)&p0; cv.u.y = *(unsigned*)&p1;
      cv.u.z = *(unsigned*)&p2; cv.u.w = *(unsigned*)&p3;
      af[k0] = cv.v;
    }
    #pragma unroll
    for (int k0 = 0; k0 < 4; k0++){
      #pragma unroll
      for (int t = 0; t < 8; t++){
        h8 bf = *(const h8*)&Wsw0[((size_t)(k0 * 8 + t) * 64 + lane) * 8];
        acc[t] = __builtin_amdgcn_mfma_f32_16x16x32_f16(af[k0], bf, acc[t], 0, 0, 0);
      }
    }
    #pragma unroll
    for (int t = 0; t < 8; t++){
      #pragma unroll
      for (int r = 0; r < 4; r++)
        lds[quad * 4 + r][t * 16 + l15] = (_Float16)acc[t][r];
    }
    #pragma unroll
    for (int it = 0; it < 4; it++){
      int idx = it * 64 + lane;
      int row = idx >> 4;
      int ch  = idx & 15;
      *(uint4*)&C[(size_t)(m0 + row) * D + ch * 8] = *(uint4*)&lds[row][ch * 8];
    }
    return;
  }
  bid -= gb;
  if (bid < npart){
    // ---- bucket histogram ----
    int* h = (int*)smraw;
    int t = threadIdx.x;
    for (int i = t; i < MAXBK; i += 256) h[i] = 0;
    __syncthreads();
    int e0 = bid * PCH;
    #pragma unroll
    for (int j = 0; j < PCH / 256; j++){
      int e = e0 + t + j * 256;
      if (e < E) atomicAdd(&h[dst[e] >> BKSHIFT], 1);
    }
    __syncthreads();
    for (int i = t; i < MAXBK; i += 256) if (h[i]) atomicAdd(&bcnt[i], h[i]);
    return;
  }
  bid -= npart;
  // ---- W1/W2 swizzle: bid 0,1 -> W1; 2,3 -> W2; 16 pairs per block ----
  const float* W = (bid < 2) ? W1 : W2;
  _Float16* dstp = Wsw12 + ((bid < 2) ? 0 : 16384);
  int pbase = (bid & 1) * 16;
  int lane = threadIdx.x & 63;
  for (int pp = (threadIdx.x >> 6); pp < 16; pp += 4)
    wcvt_pair(W, dstp, pbase + pp, lane);
}

// 2) scan bucket counts -> bOff[nbk+1], bCur; row_ptr[N]=E; zero pk
__global__ __launch_bounds__(256) void k_bscan(const int* __restrict__ bcnt,
    int* __restrict__ bOff, int* __restrict__ bCur, int* __restrict__ row_ptr,
    unsigned* __restrict__ pk, int nbk, int N, int E){
  __shared__ int sh[256];
  int t = threadIdx.x;
  for (int i = t; i < NGRAPHS * D; i += 256) pk[i] = 0u;
  int v = (t < nbk) ? bcnt[t] : 0;
  sh[t] = v; __syncthreads();
  for (int off = 1; off < 256; off <<= 1){
    int x = (t >= off) ? sh[t - off] : 0;
    __syncthreads();
    sh[t] += x;
    __syncthreads();
  }
  if (t < nbk){ int ex = sh[t] - v; bOff[t] = ex; bCur[t] = ex; }
  if (t == 0){ bOff[nbk] = E; row_ptr[N] = E; }
}

// 3) partition edges into bucket-grouped epart[] with LDS-staged coalesced writes
__global__ __launch_bounds__(256) void k_part(const int* __restrict__ src,
    const int* __restrict__ dst, int* __restrict__ bCur,
    uint2* __restrict__ epart, int E){
  __shared__ int scnt[MAXBK], soff[MAXBK], sbase[MAXBK], scur[MAXBK];
  __shared__ int stmp[256];
  __shared__ uint2 stage[PCH];   // 32 KB
  int t = threadIdx.x;
  int e0 = blockIdx.x * PCH;
  int eN = E - e0; if (eN > PCH) eN = PCH;
  for (int i = t; i < MAXBK; i += 256){ scnt[i] = 0; scur[i] = 0; }
  __syncthreads();
  uint2 mye[PCH / 256];
  #pragma unroll
  for (int j = 0; j < PCH / 256; j++){
    int e = e0 + t + j * 256;
    if (e < E){
      mye[j].x = (unsigned)src[e];
      mye[j].y = (unsigned)dst[e];
      atomicAdd(&scnt[mye[j].y >> BKSHIFT], 1);
    }
  }
  __syncthreads();
  int v = scnt[t];
  stmp[t] = v; __syncthreads();
  for (int off = 1; off < 256; off <<= 1){
    int x = (t >= off) ? stmp[t - off] : 0;
    __syncthreads();
    stmp[t] += x;
    __syncthreads();
  }
  soff[t] = stmp[t] - v;
  if (v > 0) sbase[t] = atomicAdd(&bCur[t], v);
  __syncthreads();
  #pragma unroll
  for (int j = 0; j < PCH / 256; j++){
    int e = e0 + t + j * 256;
    if (e < E){
      int b = mye[j].y >> BKSHIFT;
      int l = atomicAdd(&scur[b], 1);
      stage[soff[b] + l] = mye[j];
    }
  }
  __syncthreads();
  for (int j = t; j < eN; j += 256){
    uint2 ed = stage[j];
    int b = (int)(ed.y >> BKSHIFT);
    epart[(size_t)sbase[b] + (j - soff[b])] = ed;
  }
}

// 4) per-bucket CSR build: row_ptr, col, dinv — all state in LDS, confined writes
__global__ __launch_bounds__(256) void k_bfill(const uint2* __restrict__ epart,
    const int* __restrict__ bOff, int* __restrict__ row_ptr,
    int* __restrict__ col, float* __restrict__ dinv, int N){
  __shared__ int hc[BKNODES], off[BKNODES], cur[BKNODES];
  __shared__ int stmp[256];
  int b = blockIdx.x, t = threadIdx.x;
  int base = bOff[b], cntE = bOff[b + 1] - base;
  int node0 = b << BKSHIFT;
  int nloc = N - node0; if (nloc > BKNODES) nloc = BKNODES;
  for (int i = t; i < BKNODES; i += 256) hc[i] = 0;
  __syncthreads();
  for (int j = t; j < cntE; j += 256){
    uint2 ed = epart[(size_t)base + j];
    atomicAdd(&hc[ed.y - node0], 1);
  }
  __syncthreads();
  int a0 = hc[2 * t], a1 = hc[2 * t + 1];
  int s = a0 + a1;
  stmp[t] = s; __syncthreads();
  for (int o = 1; o < 256; o <<= 1){
    int x = (t >= o) ? stmp[t - o] : 0;
    __syncthreads();
    stmp[t] += x;
    __syncthreads();
  }
  int ex = stmp[t] - s;
  off[2 * t] = ex; off[2 * t + 1] = ex + a0;
  __syncthreads();
  for (int i = t; i < nloc; i += 256){
    row_ptr[node0 + i] = base + off[i];
    dinv[node0 + i]    = rsqrtf((float)hc[i] + 1.0f);
    cur[i] = off[i];
  }
  __syncthreads();
  for (int j = t; j < cntE; j += 256){
    uint2 ed = epart[(size_t)base + j];
    int p = atomicAdd(&cur[ed.y - node0], 1);
    col[base + p] = (int)ed.x;
  }
}

// accumulate 8 halves * w into acc[8]; (float)h * w + acc -> v_fma_mix_f32
__device__ __forceinline__ void accm(float* acc, uint4 u, float w){
  union { uint4 u; _Float16 h[8]; } cv;
  cv.u = u;
  #pragma unroll
  for (int k = 0; k < 8; k++)
    acc[k] += (float)cv.h[k] * w;
}

// gather+reduce one node into acc[8] (way-split across the wave)
__device__ __forceinline__ void agg_node(const __half* __restrict__ t,
    const int* __restrict__ col, const float* __restrict__ dinv,
    float di, int beg, int end, int way, int cg, float* acc){
  int j = beg + way;
  for (; j + 12 < end; j += 16){
    int s0 = col[j], s1 = col[j + 4], s2 = col[j + 8], s3 = col[j + 12];
    float w0 = dinv[s0] * di;
    float w1 = dinv[s1] * di;
    float w2 = dinv[s2] * di;
    float w3 = dinv[s3] * di;
    uint4 u0 = *(const uint4*)&t[(size_t)s0 * D + cg];
    uint4 u1 = *(const uint4*)&t[(size_t)s1 * D + cg];
    uint4 u2 = *(const uint4*)&t[(size_t)s2 * D + cg];
    uint4 u3 = *(const uint4*)&t[(size_t)s3 * D + cg];
    accm(acc, u0, w0);
    accm(acc, u1, w1);
    accm(acc, u2, w2);
    accm(acc, u3, w3);
  }
  for (; j < end; j += 4){
    int s = col[j];
    float w = dinv[s] * di;
    uint4 u = *(const uint4*)&t[(size_t)s * D + cg];
    accm(acc, u, w);
  }
}

// 5) FUSED agg(relu) + next-layer MFMA GEMM.
//    Block = 16 nodes; wave aggregates 4 nodes -> fp16 LDS tile -> 16x128 @ 128x128.
__global__ __launch_bounds__(256) void k_agg_gemm(const __half* __restrict__ t,
    const int* __restrict__ row_ptr, const int* __restrict__ col,
    const float* __restrict__ dinv, const float* __restrict__ bias,
    const _Float16* __restrict__ Wsw, _Float16* __restrict__ C, int N){
  __shared__ _Float16 ldsA[16][136];
  int tid = threadIdx.x;
  int wave = tid >> 6;
  int lane = tid & 63;
  int way  = lane >> 4;
  int l15  = lane & 15;
  int cg   = l15 * 8;
  int m0 = blockIdx.x * 16;
  // ---- aggregation phase: 4 nodes per wave ----
  for (int nn = 0; nn < 4; nn++){
    int node = m0 + wave * 4 + nn;
    float acc[8] = {0.f,0.f,0.f,0.f,0.f,0.f,0.f,0.f};
    float di = 0.f; int beg = 0, end = 0;
    if (node < N){
      di = dinv[node];
      beg = row_ptr[node]; end = row_ptr[node + 1];
    }
    agg_node(t, col, dinv, di, beg, end, way, cg, acc);
    #pragma unroll
    for (int k = 0; k < 8; k++){
      acc[k] += __shfl_xor(acc[k], 16, 64);
      acc[k] += __shfl_xor(acc[k], 32, 64);
    }
    if (way == 0){
      float o[8] = {0,0,0,0,0,0,0,0};
      if (node < N){
        uint4 su = *(const uint4*)&t[(size_t)node * D + cg];
        union { uint4 u; _Float16 h[8]; } sv; sv.u = su;
        float dii = di * di;
        float4 b0 = *(const float4*)&bias[cg];
        float4 b1 = *(const float4*)&bias[cg + 4];
        float bb[8] = {b0.x, b0.y, b0.z, b0.w, b1.x, b1.y, b1.z, b1.w};
        #pragma unroll
        for (int k = 0; k < 8; k++)
          o[k] = fmaxf(acc[k] + (float)sv.h[k] * dii + bb[k], 0.f);   // relu
      }
      __half2 p0 = __floats2half2_rn(o[0], o[1]);
      __half2 p1 = __floats2half2_rn(o[2], o[3]);
      __half2 p2 = __floats2half2_rn(o[4], o[5]);
      __half2 p3 = __floats2half2_rn(o[6], o[7]);
      uint4 u;
      u.x = *(unsigned*)&p0; u.y = *(unsigned*)&p1;
      u.z = *(unsigned*)&p2; u.w = *(unsigned*)&p3;
      *(uint4*)&ldsA[wave * 4 + nn][cg] = u;
    }
  }
  __syncthreads();
  // ---- GEMM phase: tile(16x128) @ Wsw -> C rows m0..m0+15 ----
  h8 af[4];
  #pragma unroll
  for (int k0 = 0; k0 < 4; k0++)
    af[k0] = *(const h8*)&ldsA[l15][k0 * 32 + way * 8];
  __syncthreads();
  f4 a0 = {}, a1 = {};
  #pragma unroll
  for (int k0 = 0; k0 < 4; k0++){
    h8 bf0 = *(const h8*)&Wsw[((size_t)(k0 * 8 + wave * 2    ) * 64 + lane) * 8];
    h8 bf1 = *(const h8*)&Wsw[((size_t)(k0 * 8 + wave * 2 + 1) * 64 + lane) * 8];
    a0 = __builtin_amdgcn_mfma_f32_16x16x32_f16(af[k0], bf0, a0, 0, 0, 0);
    a1 = __builtin_amdgcn_mfma_f32_16x16x32_f16(af[k0], bf1, a1, 0, 0, 0);
  }
  #pragma unroll
  for (int r = 0; r < 4; r++){
    ldsA[way * 4 + r][(wave * 2    ) * 16 + l15] = (_Float16)a0[r];
    ldsA[way * 4 + r][(wave * 2 + 1) * 16 + l15] = (_Float16)a1[r];
  }
  __syncthreads();
  int row = tid >> 4, ch = tid & 15;
  if (m0 + row < N)
    *(uint4*)&C[(size_t)(m0 + row) * D + ch * 8] = *(uint4*)&ldsA[row][ch * 8];
}

// 6) standalone CSR aggregation (layer 2, no relu), fp16 out.
__global__ __launch_bounds__(256) void k_agg(const __half* __restrict__ t,
    const int* __restrict__ row_ptr, const int* __restrict__ col,
    const float* __restrict__ dinv, const float* __restrict__ bias,
    __half* __restrict__ outh, int N){
  int node = blockIdx.x * 4 + (threadIdx.x >> 6);
  if (node >= N) return;
  int lane = threadIdx.x & 63;
  int way  = lane >> 4;
  int cg   = (lane & 15) * 8;
  float di = dinv[node];
  int beg = row_ptr[node], end = row_ptr[node + 1];
  float acc[8] = {0.f,0.f,0.f,0.f,0.f,0.f,0.f,0.f};
  agg_node(t, col, dinv, di, beg, end, way, cg, acc);
  #pragma unroll
  for (int k = 0; k < 8; k++){
    acc[k] += __shfl_xor(acc[k], 16, 64);
    acc[k] += __shfl_xor(acc[k], 32, 64);
  }
  if (way == 0){
    uint4 su = *(const uint4*)&t[(size_t)node * D + cg];
    union { uint4 u; _Float16 h[8]; } sv; sv.u = su;
    float dii = di * di;
    float4 b0 = *(const float4*)&bias[cg];
    float4 b1 = *(const float4*)&bias[cg + 4];
    float bb[8] = {b0.x, b0.y, b0.z, b0.w, b1.x, b1.y, b1.z, b1.w};
    float o[8];
    #pragma unroll
    for (int k = 0; k < 8; k++)
      o[k] = acc[k] + (float)sv.h[k] * dii + bb[k];
    __half2 p0 = __floats2half2_rn(o[0], o[1]);
    __half2 p1 = __floats2half2_rn(o[2], o[3]);
    __half2 p2 = __floats2half2_rn(o[4], o[5]);
    __half2 p3 = __floats2half2_rn(o[6], o[7]);
    uint4 u;
    u.x = *(unsigned*)&p0; u.y = *(unsigned*)&p1;
    u.z = *(unsigned*)&p2; u.w = *(unsigned*)&p3;
    *(uint4*)&outh[(size_t)node * D + cg] = u;
  }
}

// 7) chunked segment-max (fp16 input), 64-row chunks, 4-deep load batching.
__global__ __launch_bounds__(128) void k_pool(const __half* __restrict__ h,
    const int* __restrict__ batch, unsigned* __restrict__ pk, int N){
  int d = threadIdx.x;
  int n0 = blockIdx.x * 64;
  int nEnd = n0 + 64; if (nEnd > N) nEnd = N;
  float cur = -FLT_MAX;
  int curg = batch[n0];
  int n = n0;
  for (; n + 3 < nEnd; n += 4){
    const __half* r = &h[(size_t)n * D + d];
    __half v0 = r[0], v1 = r[D], v2 = r[2 * D], v3 = r[3 * D];
    int g0 = batch[n], g1 = batch[n + 1], g2 = batch[n + 2], g3 = batch[n + 3];
    if (g0 != curg){ atomicMax(&pk[curg * D + d], fkey(cur)); cur = -FLT_MAX; curg = g0; }
    cur = fmaxf(cur, __half2float(v0));
    if (g1 != curg){ atomicMax(&pk[curg * D + d], fkey(cur)); cur = -FLT_MAX; curg = g1; }
    cur = fmaxf(cur, __half2float(v1));
    if (g2 != curg){ atomicMax(&pk[curg * D + d], fkey(cur)); cur = -FLT_MAX; curg = g2; }
    cur = fmaxf(cur, __half2float(v2));
    if (g3 != curg){ atomicMax(&pk[curg * D + d], fkey(cur)); cur = -FLT_MAX; curg = g3; }
    cur = fmaxf(cur, __half2float(v3));
  }
  for (; n < nEnd; n++){
    int g = batch[n];
    if (g != curg){ atomicMax(&pk[curg * D + d], fkey(cur)); cur = -FLT_MAX; curg = g; }
    cur = fmaxf(cur, __half2float(h[(size_t)n * D + d]));
  }
  atomicMax(&pk[curg * D + d], fkey(cur));
}

// 8) final: out[64,2] = pooled @ Wf + bf
__global__ __launch_bounds__(128) void k_final(const unsigned* __restrict__ pk,
    const float* __restrict__ Wf, const float* __restrict__ bf,
    float* __restrict__ out){
  int t = threadIdx.x;
  int g = t >> 1, c = t & 1;
  float s = bf[c];
  for (int k = 0; k < D; k++)
    s += funkey(pk[g * D + k]) * Wf[k * 2 + c];
  out[g * 2 + c] = s;
}

extern "C" void kernel_launch(void* const* d_in, const int* in_sizes, int n_in,
                              void* d_out, int out_size, void* d_ws, size_t ws_size,
                              hipStream_t stream){
  const float* x   = (const float*)d_in[0];
  const int*   ei  = (const int*)d_in[1];
  const int*   bat = (const int*)d_in[2];
  const float* W0  = (const float*)d_in[3];
  const float* b0  = (const float*)d_in[4];
  const float* W1  = (const float*)d_in[5];
  const float* b1  = (const float*)d_in[6];
  const float* W2  = (const float*)d_in[7];
  const float* b2  = (const float*)d_in[8];
  const float* Wf  = (const float*)d_in[9];
  const float* bf  = (const float*)d_in[10];
  int N = in_sizes[0] / D;
  int E = in_sizes[1] / 2;
  const int* srcp = ei;
  const int* dstp = ei + E;
  int nbk   = (N + BKNODES - 1) / BKNODES;
  int npart = (E + PCH - 1) / PCH;
  int gb    = (N + 63) / 64;

  char* p = (char*)d_ws;
  auto alloc = [&](size_t bytes)->char*{
    char* r = p; p += (bytes + 255) & ~(size_t)255; return r;
  };
  float*     dinv    = (float*)alloc((size_t)N * 4);
  int*       row_ptr = (int*)alloc((size_t)(N + 1) * 4);
  int*       col     = (int*)alloc((size_t)E * 4);
  uint2*     epart   = (uint2*)alloc((size_t)E * 8);
  _Float16*  tmp     = (_Float16*)alloc((size_t)N * D * 2);
  _Float16*  tmp2    = (_Float16*)alloc((size_t)N * D * 2);
  _Float16*  h16     = (_Float16*)alloc((size_t)N * D * 2);
  _Float16*  Wsw     = (_Float16*)alloc((size_t)3 * 16384 * 2);
  unsigned*  pk      = (unsigned*)alloc((size_t)NGRAPHS * D * 4);
  int*       bcnt    = (int*)alloc((size_t)MAXBK * 4);
  int*       bOff    = (int*)alloc((size_t)(MAXBK + 1) * 4);
  int*       bCur    = (int*)alloc((size_t)MAXBK * 4);

  // W0 swizzle + bcnt zero
  k_wcvt0<<<8, 256, 0, stream>>>(W0, Wsw, bcnt);
  // gemm0 || bucket histogram || W1/W2 swizzle
  k_mega<<<gb + npart + 4, 256, 0, stream>>>(x, Wsw, tmp, N, gb,
      dstp, bcnt, E, npart, W1, W2, Wsw + 16384);
  k_bscan<<<1, 256, 0, stream>>>(bcnt, bOff, bCur, row_ptr, pk, nbk, N, E);
  k_part<<<npart, 256, 0, stream>>>(srcp, dstp, bCur, epart, E);
  k_bfill<<<nbk, 256, 0, stream>>>(epart, bOff, row_ptr, col, dinv, N);

  int fblocks = (N + 15) / 16;
  // layer 0 agg (+relu) fused with layer-1 GEMM
  k_agg_gemm<<<fblocks, 256, 0, stream>>>((const __half*)tmp, row_ptr, col,
      dinv, b0, Wsw + 16384, tmp2, N);
  // layer 1 agg (+relu) fused with layer-2 GEMM
  k_agg_gemm<<<fblocks, 256, 0, stream>>>((const __half*)tmp2, row_ptr, col,
      dinv, b1, Wsw + 32768, tmp, N);
  // layer 2 agg (no relu)
  k_agg<<<(N + 3) / 4, 256, 0, stream>>>((const __half*)tmp, row_ptr, col,
      dinv, b2, (__half*)h16, N);
  // pool + classifier
  k_pool<<<(N + 63) / 64, 128, 0, stream>>>((const __half*)h16, bat, pk, N);
  k_final<<<1, 128, 0, stream>>>(pk, Wf, bf, (float*)d_out);
}